// Round 8
// baseline (732.713 us; speedup 1.0000x reference)
//
#include <hip/hip_runtime.h>
#include <hip/hip_cooperative_groups.h>

namespace cg = cooperative_groups;

#define Bn 64
#define Nn 1024
#define Cc 128

typedef _Float16 h8 __attribute__((ext_vector_type(8)));
typedef float f4v __attribute__((ext_vector_type(4)));
typedef unsigned long long u64;

struct Params {
  const float* nf; const int* adj;
  const float* Win; const float* asrc; const float* adst;
  const float* asrc2; const float* adst2;
  const float* W1; const float* b1; const float* W2; const float* b2;
  const float* Wpi; const float* bpi; const float* Wv; const float* bv;
  float* out;
  _Float16* x0; _Float16* x1; u64* pm;
  float* ai1; float* aj1; float* E1; float* G1; float* F1; float* H1;
  float* ai2; float* aj2; float* E2; float* G2; float* F2; float* H2;
  float* xmp;
};

// ---- featurize one 8-node group: x = nf @ Win (fp16 grouped), scores + exp tables ----
__device__ __forceinline__ void feat_group(
    int g, int t, const float* __restrict__ nf, const float* __restrict__ Win,
    const float* __restrict__ asrc, const float* __restrict__ adst,
    _Float16* __restrict__ X0, float* __restrict__ ai, float* __restrict__ aj,
    float* __restrict__ E, float* __restrict__ G, float* __restrict__ F, float* __restrict__ H,
    char* smem) {
  float (*red)[2][4][2] = (float(*)[2][4][2])smem;  // [4][2][4][2]
  int b = g >> 7; int n0 = (g & 127) << 3;
  int c = t >> 1; int h = t & 1;
  float w0 = Win[c], w1 = Win[Cc + c], w2 = Win[2 * Cc + c];
  float as_ = asrc[c], ad = adst[c];
  float ps[4], pd[4];
  _Float16 hv[4];
  #pragma unroll
  for (int r = 0; r < 4; r++) {
    int n = n0 + (h << 2) + r;
    const float* p = nf + ((size_t)(b << 10) + n) * 3;
    float x = p[0] * w0 + p[1] * w1 + p[2] * w2;
    hv[r] = (_Float16)x; ps[r] = x * as_; pd[r] = x * ad;
  }
  *(uint2*)(X0 + ((size_t)b << 17) + ((size_t)(g & 127) << 10) + (c << 3) + (h << 2)) = *(uint2*)hv;
  #pragma unroll
  for (int off = 32; off > 1; off >>= 1) {
    #pragma unroll
    for (int r = 0; r < 4; r++) { ps[r] += __shfl_down(ps[r], off, 64); pd[r] += __shfl_down(pd[r], off, 64); }
  }
  int lane = t & 63, wv = t >> 6;
  if (lane < 2) {
    #pragma unroll
    for (int r = 0; r < 4; r++) { red[wv][lane][r][0] = ps[r]; red[wv][lane][r][1] = pd[r]; }
  }
  __syncthreads();
  if (t < 8) {
    int hh = t >> 2, r = t & 3;
    float sa = 0.f, sd = 0.f;
    #pragma unroll
    for (int w = 0; w < 4; w++) { sa += red[w][hh][r][0]; sd += red[w][hh][r][1]; }
    int gi = (b << 10) + n0 + t;
    ai[gi] = sa; aj[gi] = sd;
    E[gi] = __expf(sa); G[gi] = __expf(0.2f * sa);
    F[gi] = __expf(sd); H[gi] = __expf(0.2f * sd);
  }
  __syncthreads();  // red reads done before next group's writes
}

// ---- layer-2 scores for one 8-node group from fp16 grouped x1 ----
__device__ __forceinline__ void scores_group(
    int g, int t, const _Float16* __restrict__ X1,
    const float* __restrict__ asrc, const float* __restrict__ adst,
    float* __restrict__ ai, float* __restrict__ aj,
    float* __restrict__ E, float* __restrict__ G, float* __restrict__ F, float* __restrict__ H,
    char* smem) {
  float (*red)[2][4][2] = (float(*)[2][4][2])smem;
  int b = g >> 7; int n0 = (g & 127) << 3;
  int c = t >> 1; int h = t & 1;
  float as_ = asrc[c], ad = adst[c];
  uint2 raw = *(const uint2*)(X1 + ((size_t)b << 17) + ((size_t)(g & 127) << 10) + (c << 3) + (h << 2));
  const _Float16* hp = (const _Float16*)&raw;
  float ps[4], pd[4];
  #pragma unroll
  for (int r = 0; r < 4; r++) { float x = (float)hp[r]; ps[r] = x * as_; pd[r] = x * ad; }
  #pragma unroll
  for (int off = 32; off > 1; off >>= 1) {
    #pragma unroll
    for (int r = 0; r < 4; r++) { ps[r] += __shfl_down(ps[r], off, 64); pd[r] += __shfl_down(pd[r], off, 64); }
  }
  int lane = t & 63, wv = t >> 6;
  if (lane < 2) {
    #pragma unroll
    for (int r = 0; r < 4; r++) { red[wv][lane][r][0] = ps[r]; red[wv][lane][r][1] = pd[r]; }
  }
  __syncthreads();
  if (t < 8) {
    int hh = t >> 2, r = t & 3;
    float sa = 0.f, sd = 0.f;
    #pragma unroll
    for (int w = 0; w < 4; w++) { sa += red[w][hh][r][0]; sd += red[w][hh][r][1]; }
    int gi = (b << 10) + n0 + t;
    ai[gi] = sa; aj[gi] = sd;
    E[gi] = __expf(sa); G[gi] = __expf(0.2f * sa);
    F[gi] = __expf(sd); H[gi] = __expf(0.2f * sd);
  }
  __syncthreads();
}

// ---- one 64-row x 128-col aggregation tile (barrier-free K-loop) ----
// out[i,c] = relu( (1/den_i) * sum_j alpha_ij * x[j,c] ),  den_i = sum_j alpha_ij
template <int LAYER>
__device__ __forceinline__ void agg_tile(
    int b, int i0, char* smem,
    const _Float16* __restrict__ X, const int* __restrict__ adj,
    const float* __restrict__ ai, const float* __restrict__ E, const float* __restrict__ G,
    const float* __restrict__ aj, const float* __restrict__ F, const float* __restrict__ H,
    u64* __restrict__ pm, _Float16* __restrict__ Y, float* __restrict__ xmp, int xslot) {
  float* s_aj = (float*)smem;                            // 4 KB
  float* s_F  = (float*)(smem + 4096);                   // 4 KB
  float* s_H  = (float*)(smem + 8192);                   // 4 KB
  unsigned char* s_pm = (unsigned char*)(smem + 12288);  // 64 x 152 B
  float* s_col = (float*)(smem + 22016);                 // 512 floats

  const int tid = threadIdx.x;
  const int lane = tid & 63, w = tid >> 6;
  const int m = lane & 15, quad = lane >> 4;
  const int gbase = b << 10;

  __syncthreads();  // previous tile/phase LDS reads complete before restaging

  ((float4*)s_aj)[tid] = ((const float4*)(aj + gbase))[tid];
  ((float4*)s_F)[tid]  = ((const float4*)(F + gbase))[tid];
  ((float4*)s_H)[tid]  = ((const float4*)(H + gbase))[tid];

  if (LAYER == 1) {
    // fused adjacency read + bit-pack; lane L packs j=16L..16L+15 of row r in-register,
    // stores direct to final LDS slot and global pm (ushort view). No LDS read-back.
    ushort* pmu = (ushort*)pm;
    #pragma unroll 4
    for (int pass = 0; pass < 16; ++pass) {
      int r = (w << 4) + pass;
      const uint4* arow = (const uint4*)(adj + ((size_t)(gbase + i0 + r) << 10));
      uint4 v0 = arow[(lane << 2) | 0], v1 = arow[(lane << 2) | 1];
      uint4 v2 = arow[(lane << 2) | 2], v3 = arow[(lane << 2) | 3];
      unsigned int bits =
          (v0.x) | (v0.y << 1) | (v0.z << 2) | (v0.w << 3) |
          (v1.x << 4) | (v1.y << 5) | (v1.z << 6) | (v1.w << 7) |
          (v2.x << 8) | (v2.y << 9) | (v2.z << 10) | (v2.w << 11) |
          (v3.x << 12) | (v3.y << 13) | (v3.z << 14) | (v3.w << 15);
      *(ushort*)(s_pm + r * 152 + (lane << 1)) = (ushort)bits;
      pmu[((size_t)(gbase + i0 + r) << 6) + lane] = (ushort)bits;
    }
  } else {
    const u64* pmg = pm + (((size_t)(gbase + i0)) << 4);
    #pragma unroll
    for (int k = tid; k < 1024; k += 256) {
      int r = k >> 4, wd = k & 15;
      *(u64*)(s_pm + r * 152 + (wd << 3)) = pmg[k];
    }
  }

  // A-gen row constants: lane owns row_rel = w*16 + m (4 quads duplicate the row)
  const int irow = (w << 4) + m;
  const int gi = gbase + i0 + irow;
  const float ai_i = ai[gi];
  const float Ed = E[gi], Gd = G[gi];   // raw; den folded into epilogue
  float dsum = 0.f;

  f4v acc[8];
  #pragma unroll
  for (int ct = 0; ct < 8; ct++) { f4v z = {0.f, 0.f, 0.f, 0.f}; acc[ct] = z; }

  const h8* xb = (const h8*)(X + ((size_t)b << 17));
  const int prow = irow * 152;
  __syncthreads();  // prologue staging visible

  for (int kt = 0; kt < 32; ++kt) {
    // B fragments straight from global (L2-resident; grouped layout == fragment layout)
    const h8* bsrc = xb + (kt << 9) + (quad << 7) + m;
    h8 bf0 = bsrc[0],  bf1 = bsrc[16], bf2 = bsrc[32],  bf3 = bsrc[48];
    h8 bf4 = bsrc[64], bf5 = bsrc[80], bf6 = bsrc[96],  bf7 = bsrc[112];
    // A fragment in-register: alpha(row=irow, j = kt*32 + quad*8 + jj)
    const int j0 = (kt << 5) + (quad << 3);
    float aw[8], fw[8], hw[8];
    *(float4*)&aw[0] = *(const float4*)&s_aj[j0]; *(float4*)&aw[4] = *(const float4*)&s_aj[j0 + 4];
    *(float4*)&fw[0] = *(const float4*)&s_F[j0];  *(float4*)&fw[4] = *(const float4*)&s_F[j0 + 4];
    *(float4*)&hw[0] = *(const float4*)&s_H[j0];  *(float4*)&hw[4] = *(const float4*)&s_H[j0 + 4];
    unsigned int mb = s_pm[prow + (kt << 2) + quad];
    h8 af;
    #pragma unroll
    for (int jj = 0; jj < 8; jj++) {
      float e = ai_i + aw[jj];
      bool pos = e > 0.f;
      float wi_ = pos ? Ed : Gd;
      float wj_ = pos ? fw[jj] : hw[jj];
      float val = ((mb >> jj) & 1u) ? wi_ * wj_ : 0.f;
      dsum += val;
      af[jj] = (_Float16)val;
    }
    acc[0] = __builtin_amdgcn_mfma_f32_16x16x32_f16(af, bf0, acc[0], 0, 0, 0);
    acc[1] = __builtin_amdgcn_mfma_f32_16x16x32_f16(af, bf1, acc[1], 0, 0, 0);
    acc[2] = __builtin_amdgcn_mfma_f32_16x16x32_f16(af, bf2, acc[2], 0, 0, 0);
    acc[3] = __builtin_amdgcn_mfma_f32_16x16x32_f16(af, bf3, acc[3], 0, 0, 0);
    acc[4] = __builtin_amdgcn_mfma_f32_16x16x32_f16(af, bf4, acc[4], 0, 0, 0);
    acc[5] = __builtin_amdgcn_mfma_f32_16x16x32_f16(af, bf5, acc[5], 0, 0, 0);
    acc[6] = __builtin_amdgcn_mfma_f32_16x16x32_f16(af, bf6, acc[6], 0, 0, 0);
    acc[7] = __builtin_amdgcn_mfma_f32_16x16x32_f16(af, bf7, acc[7], 0, 0, 0);
  }

  // per-row denominator: sum lane partials over the 4 quads (same m = same row)
  dsum += __shfl_xor(dsum, 16, 64);
  dsum += __shfl_xor(dsum, 32, 64);
  float rd[4];
  #pragma unroll
  for (int r = 0; r < 4; r++) rd[r] = 1.0f / __shfl(dsum, (quad << 2) + r, 64);

  if (LAYER == 1) {
    // direct grouped-layout store: n = i0 + w*16 + quad*4 + r, c = ct*16 + m
    const int g8 = ((i0 + (w << 4)) >> 3) + (quad >> 1);
    _Float16* yb = Y + ((size_t)b << 17) + (size_t)g8 * 1024 + ((quad & 1) << 2);
    #pragma unroll
    for (int ct = 0; ct < 8; ct++) {
      int c = (ct << 4) + m;
      _Float16 hv[4];
      #pragma unroll
      for (int r = 0; r < 4; r++) hv[r] = (_Float16)fmaxf(acc[ct][r] * rd[r], 0.f);
      *(uint2*)(yb + c * 8) = *(uint2*)hv;
    }
  } else {
    // node-mean partials: per-lane col sums, quad-reduce, LDS-combine 4 waves
    #pragma unroll
    for (int ct = 0; ct < 8; ct++) {
      float cs = (fmaxf(acc[ct][0] * rd[0], 0.f) + fmaxf(acc[ct][1] * rd[1], 0.f))
               + (fmaxf(acc[ct][2] * rd[2], 0.f) + fmaxf(acc[ct][3] * rd[3], 0.f));
      cs += __shfl_xor(cs, 16, 64);
      cs += __shfl_xor(cs, 32, 64);
      if (quad == 0) s_col[(w << 7) + (ct << 4) + m] = cs;
    }
    __syncthreads();
    if (tid < 128) {
      float s = s_col[tid] + s_col[128 + tid] + s_col[256 + tid] + s_col[384 + tid];
      xmp[(xslot << 7) + tid] = s;
    }
  }
}

// ---- MLP head for one batch ----
__device__ __forceinline__ void head_batch(
    int b, int t, char* smem, const float* __restrict__ xmp,
    const float* __restrict__ W1, const float* __restrict__ b1,
    const float* __restrict__ W2, const float* __restrict__ b2,
    const float* __restrict__ Wpi, const float* __restrict__ bpi,
    const float* __restrict__ Wv, const float* __restrict__ bv,
    float* __restrict__ out) {
  float* xs = (float*)smem;          // 128
  float* h1 = xs + 128;              // 256
  float* h2 = h1 + 256;              // 128
  float* red = h2 + 128;             // 4
  __syncthreads();  // prior LDS consumers done
  if (t < 128) {
    const float* p = xmp + ((size_t)b << 11);
    float s = 0.f;
    #pragma unroll
    for (int xb = 0; xb < 16; xb++) s += p[(xb << 7) + t];
    xs[t] = s * (1.f / 1024.f);
  }
  __syncthreads();
  float s = 0.f;
  #pragma unroll 8
  for (int k = 0; k < 128; k++) s += xs[k] * W1[k * 256 + t];
  h1[t] = fmaxf(s + b1[t], 0.f);
  __syncthreads();
  if (t < 128) {
    float s2 = 0.f;
    #pragma unroll 8
    for (int k = 0; k < 256; k++) s2 += h1[k] * W2[k * 128 + t];
    h2[t] = fmaxf(s2 + b2[t], 0.f);
  }
  __syncthreads();
  float lg[4];
  #pragma unroll
  for (int q = 0; q < 4; q++) {
    int o = t + (q << 8);
    float s3 = 0.f;
    #pragma unroll 8
    for (int k = 0; k < 128; k++) s3 += h2[k] * Wpi[k * 1024 + o];
    lg[q] = s3 + bpi[o];
  }
  float mx = fmaxf(fmaxf(lg[0], lg[1]), fmaxf(lg[2], lg[3]));
  #pragma unroll
  for (int off = 32; off > 0; off >>= 1) mx = fmaxf(mx, __shfl_down(mx, off, 64));
  if ((t & 63) == 0) red[t >> 6] = mx;
  __syncthreads();
  mx = fmaxf(fmaxf(red[0], red[1]), fmaxf(red[2], red[3]));
  __syncthreads();
  float ex[4]; float sum = 0.f;
  #pragma unroll
  for (int q = 0; q < 4; q++) { ex[q] = __expf(lg[q] - mx); sum += ex[q]; }
  #pragma unroll
  for (int off = 32; off > 0; off >>= 1) sum += __shfl_down(sum, off, 64);
  if ((t & 63) == 0) red[t >> 6] = sum;
  __syncthreads();
  sum = red[0] + red[1] + red[2] + red[3];
  float rs = 1.0f / sum;
  #pragma unroll
  for (int q = 0; q < 4; q++) out[((size_t)b << 10) + t + (q << 8)] = ex[q] * rs;
  __syncthreads();
  float vp = (t < 128) ? h2[t] * Wv[t] : 0.f;
  #pragma unroll
  for (int off = 32; off > 0; off >>= 1) vp += __shfl_down(vp, off, 64);
  if ((t & 63) == 0) red[t >> 6] = vp;
  __syncthreads();
  if (t == 0) out[65536 + b] = red[0] + red[1] + red[2] + red[3] + bv[0];
}

// ================= whole pipeline as ONE cooperative kernel (grid-stride) =================
__global__ __launch_bounds__(256) void mega(Params p) {
  __shared__ __align__(16) char smem[24064];
  cg::grid_group grid = cg::this_grid();
  const int bid = blockIdx.x;
  const int nb = gridDim.x;
  const int t = threadIdx.x;

  for (int g = bid; g < 8192; g += nb)
    feat_group(g, t, p.nf, p.Win, p.asrc, p.adst,
               p.x0, p.ai1, p.aj1, p.E1, p.G1, p.F1, p.H1, smem);
  grid.sync();

  for (int tile = bid; tile < 1024; tile += nb)
    agg_tile<1>(tile >> 4, (tile & 15) << 6, smem, p.x0, p.adj,
                p.ai1, p.E1, p.G1, p.aj1, p.F1, p.H1, p.pm, p.x1, nullptr, 0);
  grid.sync();

  for (int g = bid; g < 8192; g += nb)
    scores_group(g, t, p.x1, p.asrc2, p.adst2,
                 p.ai2, p.aj2, p.E2, p.G2, p.F2, p.H2, smem);
  grid.sync();

  for (int tile = bid; tile < 1024; tile += nb)
    agg_tile<2>(tile >> 4, (tile & 15) << 6, smem, p.x1, nullptr,
                p.ai2, p.E2, p.G2, p.aj2, p.F2, p.H2, p.pm, nullptr, p.xmp, tile);
  grid.sync();

  for (int b = bid; b < Bn; b += nb)
    head_batch(b, t, smem, p.xmp, p.W1, p.b1, p.W2, p.b2,
               p.Wpi, p.bpi, p.Wv, p.bv, p.out);
}

// ================= fallback wrappers (round-6 structure, same helpers) =================
__global__ __launch_bounds__(256) void k_feat_w(Params p) {
  __shared__ __align__(16) char smem[24064];
  feat_group(blockIdx.x, threadIdx.x, p.nf, p.Win, p.asrc, p.adst,
             p.x0, p.ai1, p.aj1, p.E1, p.G1, p.F1, p.H1, smem);
}
__global__ __launch_bounds__(256, 3) void k_agg1_w(Params p) {
  __shared__ __align__(16) char smem[24064];
  agg_tile<1>(blockIdx.y, blockIdx.x << 6, smem, p.x0, p.adj,
              p.ai1, p.E1, p.G1, p.aj1, p.F1, p.H1, p.pm, p.x1, nullptr, 0);
}
__global__ __launch_bounds__(256) void k_scores_w(Params p) {
  __shared__ __align__(16) char smem[24064];
  scores_group(blockIdx.x, threadIdx.x, p.x1, p.asrc2, p.adst2,
               p.ai2, p.aj2, p.E2, p.G2, p.F2, p.H2, smem);
}
__global__ __launch_bounds__(256, 3) void k_agg2_w(Params p) {
  __shared__ __align__(16) char smem[24064];
  agg_tile<2>(blockIdx.y, blockIdx.x << 6, smem, p.x1, nullptr,
              p.ai2, p.E2, p.G2, p.aj2, p.F2, p.H2, p.pm, nullptr, p.xmp,
              ((int)blockIdx.y << 4) + blockIdx.x);
}
__global__ __launch_bounds__(256) void k_head_w(Params p) {
  __shared__ __align__(16) char smem[24064];
  head_batch(blockIdx.x, threadIdx.x, smem, p.xmp, p.W1, p.b1, p.W2, p.b2,
             p.Wpi, p.bpi, p.Wv, p.bv, p.out);
}

extern "C" void kernel_launch(void* const* d_in, const int* in_sizes, int n_in,
                              void* d_out, int out_size, void* d_ws, size_t ws_size,
                              hipStream_t stream) {
  char* ws = (char*)d_ws;
  Params p;
  p.nf    = (const float*)d_in[0];
  p.adj   = (const int*)  d_in[1];
  p.Win   = (const float*)d_in[2];
  p.asrc  = (const float*)d_in[3];
  p.adst  = (const float*)d_in[4];
  p.asrc2 = (const float*)d_in[5];
  p.adst2 = (const float*)d_in[6];
  p.W1    = (const float*)d_in[7];
  p.b1    = (const float*)d_in[8];
  p.W2    = (const float*)d_in[9];
  p.b2    = (const float*)d_in[10];
  p.Wpi   = (const float*)d_in[11];
  p.bpi   = (const float*)d_in[12];
  p.Wv    = (const float*)d_in[13];
  p.bv    = (const float*)d_in[14];
  p.out   = (float*)d_out;
  p.x0 = (_Float16*)(ws);                                // 16.78 MB
  p.x1 = (_Float16*)(ws + 16777216);                     // 16.78 MB
  p.pm = (u64*)(ws + 33554432);                          // 8.39 MB
  char* S = ws + 41943040;
  p.ai1 = (float*)(S + 0 * 262144);
  p.aj1 = (float*)(S + 1 * 262144);
  p.E1  = (float*)(S + 2 * 262144);
  p.G1  = (float*)(S + 3 * 262144);
  p.F1  = (float*)(S + 4 * 262144);
  p.H1  = (float*)(S + 5 * 262144);
  p.ai2 = (float*)(S + 6 * 262144);
  p.aj2 = (float*)(S + 7 * 262144);
  p.E2  = (float*)(S + 8 * 262144);
  p.G2  = (float*)(S + 9 * 262144);
  p.F2  = (float*)(S + 10 * 262144);
  p.H2  = (float*)(S + 11 * 262144);
  p.xmp = (float*)(S + 12 * 262144);                     // 512 KB partials

  // size cooperative grid from the runtime's own occupancy answer (deterministic,
  // host-side, capture-safe) so the co-residency check cannot reject it.
  int mb = 0;
  hipError_t qerr = hipOccupancyMaxActiveBlocksPerMultiprocessor(&mb, mega, 256, 0);
  if (qerr != hipSuccess || mb < 1) mb = 1;
  if (mb > 4) mb = 4;
  int nb = mb * 256;
  if (nb > 1024) nb = 1024;

  void* kargs[] = { (void*)&p };
  hipError_t err = hipLaunchCooperativeKernel(mega, dim3(nb), dim3(256), kargs, 0, stream);
  if (err != hipSuccess) {
    // deterministic fallback: round-6 five-kernel path (bitwise-identical outputs)
    k_feat_w<<<8192, 256, 0, stream>>>(p);
    k_agg1_w<<<dim3(16, Bn), 256, 0, stream>>>(p);
    k_scores_w<<<8192, 256, 0, stream>>>(p);
    k_agg2_w<<<dim3(16, Bn), 256, 0, stream>>>(p);
    k_head_w<<<Bn, 256, 0, stream>>>(p);
  }
}

// Round 9
// 570.664 us; speedup vs baseline: 1.2840x; 1.2840x over previous
//
#include <hip/hip_runtime.h>

#define Bn 64
#define Nn 1024
#define Cc 128

typedef _Float16 h8 __attribute__((ext_vector_type(8)));
typedef float f4v __attribute__((ext_vector_type(4)));
typedef unsigned long long u64;

struct Params {
  const float* nf; const int* adj;
  const float* Win; const float* asrc; const float* adst;
  const float* asrc2; const float* adst2;
  const float* W1; const float* b1; const float* W2; const float* b2;
  const float* Wpi; const float* bpi; const float* Wv; const float* bv;
  float* out;
  _Float16* x0; _Float16* x1; u64* pm;
  float* ai1; float* aj1; float* E1; float* G1; float* F1; float* H1;
  float* ai2; float* aj2; float* E2; float* G2; float* F2; float* H2;
  float* xmp;
};

// ---- featurize one 8-node group: x = nf @ Win (fp16 grouped), scores + exp tables ----
__device__ __forceinline__ void feat_group(
    int g, int t, const float* __restrict__ nf, const float* __restrict__ Win,
    const float* __restrict__ asrc, const float* __restrict__ adst,
    _Float16* __restrict__ X0, float* __restrict__ ai, float* __restrict__ aj,
    float* __restrict__ E, float* __restrict__ G, float* __restrict__ F, float* __restrict__ H,
    char* smem) {
  float (*red)[2][4][2] = (float(*)[2][4][2])smem;  // [4][2][4][2]
  int b = g >> 7; int n0 = (g & 127) << 3;
  int c = t >> 1; int h = t & 1;
  float w0 = Win[c], w1 = Win[Cc + c], w2 = Win[2 * Cc + c];
  float as_ = asrc[c], ad = adst[c];
  float ps[4], pd[4];
  _Float16 hv[4];
  #pragma unroll
  for (int r = 0; r < 4; r++) {
    int n = n0 + (h << 2) + r;
    const float* p = nf + ((size_t)(b << 10) + n) * 3;
    float x = p[0] * w0 + p[1] * w1 + p[2] * w2;
    hv[r] = (_Float16)x; ps[r] = x * as_; pd[r] = x * ad;
  }
  *(uint2*)(X0 + ((size_t)b << 17) + ((size_t)(g & 127) << 10) + (c << 3) + (h << 2)) = *(uint2*)hv;
  #pragma unroll
  for (int off = 32; off > 1; off >>= 1) {
    #pragma unroll
    for (int r = 0; r < 4; r++) { ps[r] += __shfl_down(ps[r], off, 64); pd[r] += __shfl_down(pd[r], off, 64); }
  }
  int lane = t & 63, wv = t >> 6;
  if (lane < 2) {
    #pragma unroll
    for (int r = 0; r < 4; r++) { red[wv][lane][r][0] = ps[r]; red[wv][lane][r][1] = pd[r]; }
  }
  __syncthreads();
  if (t < 8) {
    int hh = t >> 2, r = t & 3;
    float sa = 0.f, sd = 0.f;
    #pragma unroll
    for (int w = 0; w < 4; w++) { sa += red[w][hh][r][0]; sd += red[w][hh][r][1]; }
    int gi = (b << 10) + n0 + t;
    ai[gi] = sa; aj[gi] = sd;
    E[gi] = __expf(sa); G[gi] = __expf(0.2f * sa);
    F[gi] = __expf(sd); H[gi] = __expf(0.2f * sd);
  }
  __syncthreads();  // red reads done before next group's writes
}

// ---- layer-2 scores for one 8-node group from fp16 grouped x1 ----
__device__ __forceinline__ void scores_group(
    int g, int t, const _Float16* __restrict__ X1,
    const float* __restrict__ asrc, const float* __restrict__ adst,
    float* __restrict__ ai, float* __restrict__ aj,
    float* __restrict__ E, float* __restrict__ G, float* __restrict__ F, float* __restrict__ H,
    char* smem) {
  float (*red)[2][4][2] = (float(*)[2][4][2])smem;
  int b = g >> 7; int n0 = (g & 127) << 3;
  int c = t >> 1; int h = t & 1;
  float as_ = asrc[c], ad = adst[c];
  uint2 raw = *(const uint2*)(X1 + ((size_t)b << 17) + ((size_t)(g & 127) << 10) + (c << 3) + (h << 2));
  const _Float16* hp = (const _Float16*)&raw;
  float ps[4], pd[4];
  #pragma unroll
  for (int r = 0; r < 4; r++) { float x = (float)hp[r]; ps[r] = x * as_; pd[r] = x * ad; }
  #pragma unroll
  for (int off = 32; off > 1; off >>= 1) {
    #pragma unroll
    for (int r = 0; r < 4; r++) { ps[r] += __shfl_down(ps[r], off, 64); pd[r] += __shfl_down(pd[r], off, 64); }
  }
  int lane = t & 63, wv = t >> 6;
  if (lane < 2) {
    #pragma unroll
    for (int r = 0; r < 4; r++) { red[wv][lane][r][0] = ps[r]; red[wv][lane][r][1] = pd[r]; }
  }
  __syncthreads();
  if (t < 8) {
    int hh = t >> 2, r = t & 3;
    float sa = 0.f, sd = 0.f;
    #pragma unroll
    for (int w = 0; w < 4; w++) { sa += red[w][hh][r][0]; sd += red[w][hh][r][1]; }
    int gi = (b << 10) + n0 + t;
    ai[gi] = sa; aj[gi] = sd;
    E[gi] = __expf(sa); G[gi] = __expf(0.2f * sa);
    F[gi] = __expf(sd); H[gi] = __expf(0.2f * sd);
  }
  __syncthreads();
}

// ---- one 64-row x 128-col aggregation tile (barrier-free K-loop, pm from global) ----
// out[i,c] = relu( (1/den_i) * sum_j alpha_ij * x[j,c] ),  den_i = sum_j alpha_ij
template <int LAYER>
__device__ __forceinline__ void agg_tile(
    int b, int i0, char* smem,
    const _Float16* __restrict__ X,
    const float* __restrict__ ai, const float* __restrict__ E, const float* __restrict__ G,
    const float* __restrict__ aj, const float* __restrict__ F, const float* __restrict__ H,
    const u64* __restrict__ pm, _Float16* __restrict__ Y, float* __restrict__ xmp, int xslot) {
  float* s_aj = (float*)smem;                            // 4 KB
  float* s_F  = (float*)(smem + 4096);                   // 4 KB
  float* s_H  = (float*)(smem + 8192);                   // 4 KB
  unsigned char* s_pm = (unsigned char*)(smem + 12288);  // 64 x 152 B
  float* s_col = (float*)(smem + 22016);                 // 512 floats

  const int tid = threadIdx.x;
  const int lane = tid & 63, w = tid >> 6;
  const int m = lane & 15, quad = lane >> 4;
  const int gbase = b << 10;

  ((float4*)s_aj)[tid] = ((const float4*)(aj + gbase))[tid];
  ((float4*)s_F)[tid]  = ((const float4*)(F + gbase))[tid];
  ((float4*)s_H)[tid]  = ((const float4*)(H + gbase))[tid];

  // stage packed mask from global pm (64 rows x 128 B -> padded stride 152)
  {
    const u64* pmg = pm + (((size_t)(gbase + i0)) << 4);
    #pragma unroll
    for (int k = tid; k < 1024; k += 256) {
      int r = k >> 4, wd = k & 15;
      *(u64*)(s_pm + r * 152 + (wd << 3)) = pmg[k];
    }
  }

  // A-gen row constants: lane owns row_rel = w*16 + m (4 quads duplicate the row)
  const int irow = (w << 4) + m;
  const int gi = gbase + i0 + irow;
  const float ai_i = ai[gi];
  const float Ed = E[gi], Gd = G[gi];   // raw; den folded into epilogue
  float dsum = 0.f;

  f4v acc[8];
  #pragma unroll
  for (int ct = 0; ct < 8; ct++) { f4v z = {0.f, 0.f, 0.f, 0.f}; acc[ct] = z; }

  const h8* xb = (const h8*)(X + ((size_t)b << 17));
  const int prow = irow * 152;
  __syncthreads();  // prologue staging visible

  for (int kt = 0; kt < 32; ++kt) {
    // B fragments straight from global (L2-resident; grouped layout == fragment layout)
    const h8* bsrc = xb + (kt << 9) + (quad << 7) + m;
    h8 bf0 = bsrc[0],  bf1 = bsrc[16], bf2 = bsrc[32],  bf3 = bsrc[48];
    h8 bf4 = bsrc[64], bf5 = bsrc[80], bf6 = bsrc[96],  bf7 = bsrc[112];
    // A fragment in-register: alpha(row=irow, j = kt*32 + quad*8 + jj)
    const int j0 = (kt << 5) + (quad << 3);
    float aw[8], fw[8], hw[8];
    *(float4*)&aw[0] = *(const float4*)&s_aj[j0]; *(float4*)&aw[4] = *(const float4*)&s_aj[j0 + 4];
    *(float4*)&fw[0] = *(const float4*)&s_F[j0];  *(float4*)&fw[4] = *(const float4*)&s_F[j0 + 4];
    *(float4*)&hw[0] = *(const float4*)&s_H[j0];  *(float4*)&hw[4] = *(const float4*)&s_H[j0 + 4];
    unsigned int mb = s_pm[prow + (kt << 2) + quad];
    h8 af;
    #pragma unroll
    for (int jj = 0; jj < 8; jj++) {
      float e = ai_i + aw[jj];
      bool pos = e > 0.f;
      float wi_ = pos ? Ed : Gd;
      float wj_ = pos ? fw[jj] : hw[jj];
      float val = ((mb >> jj) & 1u) ? wi_ * wj_ : 0.f;
      dsum += val;
      af[jj] = (_Float16)val;
    }
    acc[0] = __builtin_amdgcn_mfma_f32_16x16x32_f16(af, bf0, acc[0], 0, 0, 0);
    acc[1] = __builtin_amdgcn_mfma_f32_16x16x32_f16(af, bf1, acc[1], 0, 0, 0);
    acc[2] = __builtin_amdgcn_mfma_f32_16x16x32_f16(af, bf2, acc[2], 0, 0, 0);
    acc[3] = __builtin_amdgcn_mfma_f32_16x16x32_f16(af, bf3, acc[3], 0, 0, 0);
    acc[4] = __builtin_amdgcn_mfma_f32_16x16x32_f16(af, bf4, acc[4], 0, 0, 0);
    acc[5] = __builtin_amdgcn_mfma_f32_16x16x32_f16(af, bf5, acc[5], 0, 0, 0);
    acc[6] = __builtin_amdgcn_mfma_f32_16x16x32_f16(af, bf6, acc[6], 0, 0, 0);
    acc[7] = __builtin_amdgcn_mfma_f32_16x16x32_f16(af, bf7, acc[7], 0, 0, 0);
  }

  // per-row denominator: sum lane partials over the 4 quads (same m = same row)
  dsum += __shfl_xor(dsum, 16, 64);
  dsum += __shfl_xor(dsum, 32, 64);
  float rd[4];
  #pragma unroll
  for (int r = 0; r < 4; r++) rd[r] = 1.0f / __shfl(dsum, (quad << 2) + r, 64);

  if (LAYER == 1) {
    // direct grouped-layout store: n = i0 + w*16 + quad*4 + r, c = ct*16 + m
    const int g8 = ((i0 + (w << 4)) >> 3) + (quad >> 1);
    _Float16* yb = Y + ((size_t)b << 17) + (size_t)g8 * 1024 + ((quad & 1) << 2);
    #pragma unroll
    for (int ct = 0; ct < 8; ct++) {
      int c = (ct << 4) + m;
      _Float16 hv[4];
      #pragma unroll
      for (int r = 0; r < 4; r++) hv[r] = (_Float16)fmaxf(acc[ct][r] * rd[r], 0.f);
      *(uint2*)(yb + c * 8) = *(uint2*)hv;
    }
  } else {
    // node-mean partials: per-lane col sums, quad-reduce, LDS-combine 4 waves
    #pragma unroll
    for (int ct = 0; ct < 8; ct++) {
      float cs = (fmaxf(acc[ct][0] * rd[0], 0.f) + fmaxf(acc[ct][1] * rd[1], 0.f))
               + (fmaxf(acc[ct][2] * rd[2], 0.f) + fmaxf(acc[ct][3] * rd[3], 0.f));
      cs += __shfl_xor(cs, 16, 64);
      cs += __shfl_xor(cs, 32, 64);
      if (quad == 0) s_col[(w << 7) + (ct << 4) + m] = cs;
    }
    __syncthreads();
    if (tid < 128) {
      float s = s_col[tid] + s_col[128 + tid] + s_col[256 + tid] + s_col[384 + tid];
      xmp[(xslot << 7) + tid] = s;
    }
  }
}

// ---- MLP head for one batch ----
__device__ __forceinline__ void head_batch(
    int b, int t, char* smem, const float* __restrict__ xmp,
    const float* __restrict__ W1, const float* __restrict__ b1,
    const float* __restrict__ W2, const float* __restrict__ b2,
    const float* __restrict__ Wpi, const float* __restrict__ bpi,
    const float* __restrict__ Wv, const float* __restrict__ bv,
    float* __restrict__ out) {
  float* xs = (float*)smem;          // 128
  float* h1 = xs + 128;              // 256
  float* h2 = h1 + 256;              // 128
  float* red = h2 + 128;             // 4
  if (t < 128) {
    const float* p = xmp + ((size_t)b << 11);
    float s = 0.f;
    #pragma unroll
    for (int xb = 0; xb < 16; xb++) s += p[(xb << 7) + t];
    xs[t] = s * (1.f / 1024.f);
  }
  __syncthreads();
  float s = 0.f;
  #pragma unroll 8
  for (int k = 0; k < 128; k++) s += xs[k] * W1[k * 256 + t];
  h1[t] = fmaxf(s + b1[t], 0.f);
  __syncthreads();
  if (t < 128) {
    float s2 = 0.f;
    #pragma unroll 8
    for (int k = 0; k < 256; k++) s2 += h1[k] * W2[k * 128 + t];
    h2[t] = fmaxf(s2 + b2[t], 0.f);
  }
  __syncthreads();
  float lg[4];
  #pragma unroll
  for (int q = 0; q < 4; q++) {
    int o = t + (q << 8);
    float s3 = 0.f;
    #pragma unroll 8
    for (int k = 0; k < 128; k++) s3 += h2[k] * Wpi[k * 1024 + o];
    lg[q] = s3 + bpi[o];
  }
  float mx = fmaxf(fmaxf(lg[0], lg[1]), fmaxf(lg[2], lg[3]));
  #pragma unroll
  for (int off = 32; off > 0; off >>= 1) mx = fmaxf(mx, __shfl_down(mx, off, 64));
  if ((t & 63) == 0) red[t >> 6] = mx;
  __syncthreads();
  mx = fmaxf(fmaxf(red[0], red[1]), fmaxf(red[2], red[3]));
  __syncthreads();
  float ex[4]; float sum = 0.f;
  #pragma unroll
  for (int q = 0; q < 4; q++) { ex[q] = __expf(lg[q] - mx); sum += ex[q]; }
  #pragma unroll
  for (int off = 32; off > 0; off >>= 1) sum += __shfl_down(sum, off, 64);
  if ((t & 63) == 0) red[t >> 6] = sum;
  __syncthreads();
  sum = red[0] + red[1] + red[2] + red[3];
  float rs = 1.0f / sum;
  #pragma unroll
  for (int q = 0; q < 4; q++) out[((size_t)b << 10) + t + (q << 8)] = ex[q] * rs;
  __syncthreads();
  float vp = (t < 128) ? h2[t] * Wv[t] : 0.f;
  #pragma unroll
  for (int off = 32; off > 0; off >>= 1) vp += __shfl_down(vp, off, 64);
  if ((t & 63) == 0) red[t >> 6] = vp;
  __syncthreads();
  if (t == 0) out[65536 + b] = red[0] + red[1] + red[2] + red[3] + bv[0];
}

// ======= max-occupancy adjacency bit-pack: 2048 blocks x 32 rows, no LDS =======
// lane L packs the 16-bit mask for j=16L..16L+15 of its row; row = 4 KB read.
__global__ __launch_bounds__(256) void k_pack(const int* __restrict__ adj,
                                              ushort* __restrict__ pmu) {
  const int lane = threadIdx.x & 63, w = threadIdx.x >> 6;
  const int r0 = (blockIdx.x << 5) + (w << 3);   // 8 rows per wave
  #pragma unroll
  for (int rr = 0; rr < 8; ++rr) {
    const int rg = r0 + rr;
    const uint4* arow = (const uint4*)(adj + ((size_t)rg << 10));
    uint4 v0 = arow[(lane << 2) | 0], v1 = arow[(lane << 2) | 1];
    uint4 v2 = arow[(lane << 2) | 2], v3 = arow[(lane << 2) | 3];
    unsigned int bits =
        (v0.x) | (v0.y << 1) | (v0.z << 2) | (v0.w << 3) |
        (v1.x << 4) | (v1.y << 5) | (v1.z << 6) | (v1.w << 7) |
        (v2.x << 8) | (v2.y << 9) | (v2.z << 10) | (v2.w << 11) |
        (v3.x << 12) | (v3.y << 13) | (v3.z << 14) | (v3.w << 15);
    pmu[((size_t)rg << 6) + lane] = (ushort)bits;
  }
}

// ======= plain kernels (all <= 2048 blocks; no cooperative sync) =======
__global__ __launch_bounds__(256) void k_feat_w(Params p) {
  __shared__ __align__(16) char smem[24064];
  #pragma unroll 1
  for (int i = 0; i < 8; ++i)
    feat_group((blockIdx.x << 3) + i, threadIdx.x, p.nf, p.Win, p.asrc, p.adst,
               p.x0, p.ai1, p.aj1, p.E1, p.G1, p.F1, p.H1, smem);
}
__global__ __launch_bounds__(256, 3) void k_agg1_w(Params p) {
  __shared__ __align__(16) char smem[24064];
  agg_tile<1>(blockIdx.y, blockIdx.x << 6, smem, p.x0,
              p.ai1, p.E1, p.G1, p.aj1, p.F1, p.H1, p.pm, p.x1, nullptr, 0);
}
__global__ __launch_bounds__(256) void k_scores_w(Params p) {
  __shared__ __align__(16) char smem[24064];
  #pragma unroll 1
  for (int i = 0; i < 8; ++i)
    scores_group((blockIdx.x << 3) + i, threadIdx.x, p.x1, p.asrc2, p.adst2,
                 p.ai2, p.aj2, p.E2, p.G2, p.F2, p.H2, smem);
}
__global__ __launch_bounds__(256, 3) void k_agg2_w(Params p) {
  __shared__ __align__(16) char smem[24064];
  agg_tile<2>(blockIdx.y, blockIdx.x << 6, smem, p.x1,
              p.ai2, p.E2, p.G2, p.aj2, p.F2, p.H2, p.pm, nullptr, p.xmp,
              ((int)blockIdx.y << 4) + blockIdx.x);
}
__global__ __launch_bounds__(256) void k_head_w(Params p) {
  __shared__ __align__(16) char smem[24064];
  head_batch(blockIdx.x, threadIdx.x, smem, p.xmp, p.W1, p.b1, p.W2, p.b2,
             p.Wpi, p.bpi, p.Wv, p.bv, p.out);
}

extern "C" void kernel_launch(void* const* d_in, const int* in_sizes, int n_in,
                              void* d_out, int out_size, void* d_ws, size_t ws_size,
                              hipStream_t stream) {
  char* ws = (char*)d_ws;
  Params p;
  p.nf    = (const float*)d_in[0];
  p.adj   = (const int*)  d_in[1];
  p.Win   = (const float*)d_in[2];
  p.asrc  = (const float*)d_in[3];
  p.adst  = (const float*)d_in[4];
  p.asrc2 = (const float*)d_in[5];
  p.adst2 = (const float*)d_in[6];
  p.W1    = (const float*)d_in[7];
  p.b1    = (const float*)d_in[8];
  p.W2    = (const float*)d_in[9];
  p.b2    = (const float*)d_in[10];
  p.Wpi   = (const float*)d_in[11];
  p.bpi   = (const float*)d_in[12];
  p.Wv    = (const float*)d_in[13];
  p.bv    = (const float*)d_in[14];
  p.out   = (float*)d_out;
  p.x0 = (_Float16*)(ws);                                // 16.78 MB
  p.x1 = (_Float16*)(ws + 16777216);                     // 16.78 MB
  p.pm = (u64*)(ws + 33554432);                          // 8.39 MB
  char* S = ws + 41943040;
  p.ai1 = (float*)(S + 0 * 262144);
  p.aj1 = (float*)(S + 1 * 262144);
  p.E1  = (float*)(S + 2 * 262144);
  p.G1  = (float*)(S + 3 * 262144);
  p.F1  = (float*)(S + 4 * 262144);
  p.H1  = (float*)(S + 5 * 262144);
  p.ai2 = (float*)(S + 6 * 262144);
  p.aj2 = (float*)(S + 7 * 262144);
  p.E2  = (float*)(S + 8 * 262144);
  p.G2  = (float*)(S + 9 * 262144);
  p.F2  = (float*)(S + 10 * 262144);
  p.H2  = (float*)(S + 11 * 262144);
  p.xmp = (float*)(S + 12 * 262144);                     // 512 KB partials

  k_pack<<<2048, 256, 0, stream>>>(p.adj, (ushort*)p.pm);
  k_feat_w<<<1024, 256, 0, stream>>>(p);
  k_agg1_w<<<dim3(16, Bn), 256, 0, stream>>>(p);
  k_scores_w<<<1024, 256, 0, stream>>>(p);
  k_agg2_w<<<dim3(16, Bn), 256, 0, stream>>>(p);
  k_head_w<<<Bn, 256, 0, stream>>>(p);
}

// Round 10
// 567.761 us; speedup vs baseline: 1.2905x; 1.0051x over previous
//
#include <hip/hip_runtime.h>

#define Bn 64
#define Nn 1024
#define Cc 128

typedef _Float16 h8 __attribute__((ext_vector_type(8)));
typedef float f4v __attribute__((ext_vector_type(4)));
typedef unsigned long long u64;

struct Params {
  const float* nf; const int* adj;
  const float* Win; const float* asrc; const float* adst;
  const float* asrc2; const float* adst2;
  const float* W1; const float* b1; const float* W2; const float* b2;
  const float* Wpi; const float* bpi; const float* Wv; const float* bv;
  float* out;
  _Float16* x0; _Float16* x1; u64* pm;
  float* ai1; float* aj1; float* E1; float* G1; float* F1; float* H1;
  float* ai2; float* aj2; float* E2; float* G2; float* F2; float* H2;
  float* xmp;
};

// ---- featurize one 8-node group: x = nf @ Win (fp16 grouped), scores + exp tables ----
__device__ __forceinline__ void feat_group(
    int g, int t, const float* __restrict__ nf, const float* __restrict__ Win,
    const float* __restrict__ asrc, const float* __restrict__ adst,
    _Float16* __restrict__ X0, float* __restrict__ ai, float* __restrict__ aj,
    float* __restrict__ E, float* __restrict__ G, float* __restrict__ F, float* __restrict__ H,
    char* smem) {
  float (*red)[2][4][2] = (float(*)[2][4][2])smem;  // [4][2][4][2] = 512 B
  int b = g >> 7; int n0 = (g & 127) << 3;
  int c = t >> 1; int h = t & 1;
  float w0 = Win[c], w1 = Win[Cc + c], w2 = Win[2 * Cc + c];
  float as_ = asrc[c], ad = adst[c];
  float ps[4], pd[4];
  _Float16 hv[4];
  #pragma unroll
  for (int r = 0; r < 4; r++) {
    int n = n0 + (h << 2) + r;
    const float* p = nf + ((size_t)(b << 10) + n) * 3;
    float x = p[0] * w0 + p[1] * w1 + p[2] * w2;
    hv[r] = (_Float16)x; ps[r] = x * as_; pd[r] = x * ad;
  }
  *(uint2*)(X0 + ((size_t)b << 17) + ((size_t)(g & 127) << 10) + (c << 3) + (h << 2)) = *(uint2*)hv;
  #pragma unroll
  for (int off = 32; off > 1; off >>= 1) {
    #pragma unroll
    for (int r = 0; r < 4; r++) { ps[r] += __shfl_down(ps[r], off, 64); pd[r] += __shfl_down(pd[r], off, 64); }
  }
  int lane = t & 63, wv = t >> 6;
  if (lane < 2) {
    #pragma unroll
    for (int r = 0; r < 4; r++) { red[wv][lane][r][0] = ps[r]; red[wv][lane][r][1] = pd[r]; }
  }
  __syncthreads();
  if (t < 8) {
    int hh = t >> 2, r = t & 3;
    float sa = 0.f, sd = 0.f;
    #pragma unroll
    for (int w = 0; w < 4; w++) { sa += red[w][hh][r][0]; sd += red[w][hh][r][1]; }
    int gi = (b << 10) + n0 + t;
    ai[gi] = sa; aj[gi] = sd;
    E[gi] = __expf(sa); G[gi] = __expf(0.2f * sa);
    F[gi] = __expf(sd); H[gi] = __expf(0.2f * sd);
  }
  __syncthreads();  // red reads done before next group's writes
}

// ---- layer-2 scores for one 8-node group from fp16 grouped x1 ----
__device__ __forceinline__ void scores_group(
    int g, int t, const _Float16* __restrict__ X1,
    const float* __restrict__ asrc, const float* __restrict__ adst,
    float* __restrict__ ai, float* __restrict__ aj,
    float* __restrict__ E, float* __restrict__ G, float* __restrict__ F, float* __restrict__ H,
    char* smem) {
  float (*red)[2][4][2] = (float(*)[2][4][2])smem;
  int b = g >> 7; int n0 = (g & 127) << 3;
  int c = t >> 1; int h = t & 1;
  float as_ = asrc[c], ad = adst[c];
  uint2 raw = *(const uint2*)(X1 + ((size_t)b << 17) + ((size_t)(g & 127) << 10) + (c << 3) + (h << 2));
  const _Float16* hp = (const _Float16*)&raw;
  float ps[4], pd[4];
  #pragma unroll
  for (int r = 0; r < 4; r++) { float x = (float)hp[r]; ps[r] = x * as_; pd[r] = x * ad; }
  #pragma unroll
  for (int off = 32; off > 1; off >>= 1) {
    #pragma unroll
    for (int r = 0; r < 4; r++) { ps[r] += __shfl_down(ps[r], off, 64); pd[r] += __shfl_down(pd[r], off, 64); }
  }
  int lane = t & 63, wv = t >> 6;
  if (lane < 2) {
    #pragma unroll
    for (int r = 0; r < 4; r++) { red[wv][lane][r][0] = ps[r]; red[wv][lane][r][1] = pd[r]; }
  }
  __syncthreads();
  if (t < 8) {
    int hh = t >> 2, r = t & 3;
    float sa = 0.f, sd = 0.f;
    #pragma unroll
    for (int w = 0; w < 4; w++) { sa += red[w][hh][r][0]; sd += red[w][hh][r][1]; }
    int gi = (b << 10) + n0 + t;
    ai[gi] = sa; aj[gi] = sd;
    E[gi] = __expf(sa); G[gi] = __expf(0.2f * sa);
    F[gi] = __expf(sd); H[gi] = __expf(0.2f * sd);
  }
  __syncthreads();
}

// ---- one 64-row x 128-col aggregation tile (barrier-free K-loop, pm from global) ----
// out[i,c] = relu( (1/den_i) * sum_j alpha_ij * x[j,c] ),  den_i = sum_j alpha_ij
template <int LAYER>
__device__ __forceinline__ void agg_tile(
    int b, int i0, char* smem,
    const _Float16* __restrict__ X,
    const float* __restrict__ ai, const float* __restrict__ E, const float* __restrict__ G,
    const float* __restrict__ aj, const float* __restrict__ F, const float* __restrict__ H,
    const u64* __restrict__ pm, _Float16* __restrict__ Y, float* __restrict__ xmp, int xslot) {
  float* s_aj = (float*)smem;                            // 4 KB
  float* s_F  = (float*)(smem + 4096);                   // 4 KB
  float* s_H  = (float*)(smem + 8192);                   // 4 KB
  unsigned char* s_pm = (unsigned char*)(smem + 12288);  // 64 x 152 B
  float* s_col = (float*)(smem + 22016);                 // 512 floats

  const int tid = threadIdx.x;
  const int lane = tid & 63, w = tid >> 6;
  const int m = lane & 15, quad = lane >> 4;
  const int gbase = b << 10;

  ((float4*)s_aj)[tid] = ((const float4*)(aj + gbase))[tid];
  ((float4*)s_F)[tid]  = ((const float4*)(F + gbase))[tid];
  ((float4*)s_H)[tid]  = ((const float4*)(H + gbase))[tid];

  // stage packed mask from global pm (64 rows x 128 B -> padded stride 152)
  {
    const u64* pmg = pm + (((size_t)(gbase + i0)) << 4);
    #pragma unroll
    for (int k = tid; k < 1024; k += 256) {
      int r = k >> 4, wd = k & 15;
      *(u64*)(s_pm + r * 152 + (wd << 3)) = pmg[k];
    }
  }

  // A-gen row constants: lane owns row_rel = w*16 + m (4 quads duplicate the row)
  const int irow = (w << 4) + m;
  const int gi = gbase + i0 + irow;
  const float ai_i = ai[gi];
  const float Ed = E[gi], Gd = G[gi];   // raw; den folded into epilogue
  float dsum = 0.f;

  f4v acc[8];
  #pragma unroll
  for (int ct = 0; ct < 8; ct++) { f4v z = {0.f, 0.f, 0.f, 0.f}; acc[ct] = z; }

  const h8* xb = (const h8*)(X + ((size_t)b << 17));
  const int prow = irow * 152;
  __syncthreads();  // prologue staging visible

  for (int kt = 0; kt < 32; ++kt) {
    // B fragments straight from global (L2/L3-resident; grouped layout == fragment layout)
    const h8* bsrc = xb + (kt << 9) + (quad << 7) + m;
    h8 bf0 = bsrc[0],  bf1 = bsrc[16], bf2 = bsrc[32],  bf3 = bsrc[48];
    h8 bf4 = bsrc[64], bf5 = bsrc[80], bf6 = bsrc[96],  bf7 = bsrc[112];
    // A fragment in-register: alpha(row=irow, j = kt*32 + quad*8 + jj)
    const int j0 = (kt << 5) + (quad << 3);
    float aw[8], fw[8], hw[8];
    *(float4*)&aw[0] = *(const float4*)&s_aj[j0]; *(float4*)&aw[4] = *(const float4*)&s_aj[j0 + 4];
    *(float4*)&fw[0] = *(const float4*)&s_F[j0];  *(float4*)&fw[4] = *(const float4*)&s_F[j0 + 4];
    *(float4*)&hw[0] = *(const float4*)&s_H[j0];  *(float4*)&hw[4] = *(const float4*)&s_H[j0 + 4];
    unsigned int mb = s_pm[prow + (kt << 2) + quad];
    h8 af;
    #pragma unroll
    for (int jj = 0; jj < 8; jj++) {
      float e = ai_i + aw[jj];
      bool pos = e > 0.f;
      float wi_ = pos ? Ed : Gd;
      float wj_ = pos ? fw[jj] : hw[jj];
      float val = ((mb >> jj) & 1u) ? wi_ * wj_ : 0.f;
      dsum += val;
      af[jj] = (_Float16)val;
    }
    acc[0] = __builtin_amdgcn_mfma_f32_16x16x32_f16(af, bf0, acc[0], 0, 0, 0);
    acc[1] = __builtin_amdgcn_mfma_f32_16x16x32_f16(af, bf1, acc[1], 0, 0, 0);
    acc[2] = __builtin_amdgcn_mfma_f32_16x16x32_f16(af, bf2, acc[2], 0, 0, 0);
    acc[3] = __builtin_amdgcn_mfma_f32_16x16x32_f16(af, bf3, acc[3], 0, 0, 0);
    acc[4] = __builtin_amdgcn_mfma_f32_16x16x32_f16(af, bf4, acc[4], 0, 0, 0);
    acc[5] = __builtin_amdgcn_mfma_f32_16x16x32_f16(af, bf5, acc[5], 0, 0, 0);
    acc[6] = __builtin_amdgcn_mfma_f32_16x16x32_f16(af, bf6, acc[6], 0, 0, 0);
    acc[7] = __builtin_amdgcn_mfma_f32_16x16x32_f16(af, bf7, acc[7], 0, 0, 0);
  }

  // per-row denominator: sum lane partials over the 4 quads (same m = same row)
  dsum += __shfl_xor(dsum, 16, 64);
  dsum += __shfl_xor(dsum, 32, 64);
  float rd[4];
  #pragma unroll
  for (int r = 0; r < 4; r++) rd[r] = 1.0f / __shfl(dsum, (quad << 2) + r, 64);

  if (LAYER == 1) {
    // direct grouped-layout store: n = i0 + w*16 + quad*4 + r, c = ct*16 + m
    const int g8 = ((i0 + (w << 4)) >> 3) + (quad >> 1);
    _Float16* yb = Y + ((size_t)b << 17) + (size_t)g8 * 1024 + ((quad & 1) << 2);
    #pragma unroll
    for (int ct = 0; ct < 8; ct++) {
      int c = (ct << 4) + m;
      _Float16 hv[4];
      #pragma unroll
      for (int r = 0; r < 4; r++) hv[r] = (_Float16)fmaxf(acc[ct][r] * rd[r], 0.f);
      *(uint2*)(yb + c * 8) = *(uint2*)hv;
    }
  } else {
    // node-mean partials: per-lane col sums, quad-reduce, LDS-combine 4 waves
    #pragma unroll
    for (int ct = 0; ct < 8; ct++) {
      float cs = (fmaxf(acc[ct][0] * rd[0], 0.f) + fmaxf(acc[ct][1] * rd[1], 0.f))
               + (fmaxf(acc[ct][2] * rd[2], 0.f) + fmaxf(acc[ct][3] * rd[3], 0.f));
      cs += __shfl_xor(cs, 16, 64);
      cs += __shfl_xor(cs, 32, 64);
      if (quad == 0) s_col[(w << 7) + (ct << 4) + m] = cs;
    }
    __syncthreads();
    if (tid < 128) {
      float s = s_col[tid] + s_col[128 + tid] + s_col[256 + tid] + s_col[384 + tid];
      xmp[(xslot << 7) + tid] = s;
    }
  }
}

// ---- MLP head for one batch ----
__device__ __forceinline__ void head_batch(
    int b, int t, char* smem, const float* __restrict__ xmp,
    const float* __restrict__ W1, const float* __restrict__ b1,
    const float* __restrict__ W2, const float* __restrict__ b2,
    const float* __restrict__ Wpi, const float* __restrict__ bpi,
    const float* __restrict__ Wv, const float* __restrict__ bv,
    float* __restrict__ out) {
  float* xs = (float*)smem;          // 128
  float* h1 = xs + 128;              // 256
  float* h2 = h1 + 256;              // 128
  float* red = h2 + 128;             // 4
  if (t < 128) {
    const float* p = xmp + ((size_t)b << 11);
    float s = 0.f;
    #pragma unroll
    for (int xb = 0; xb < 16; xb++) s += p[(xb << 7) + t];
    xs[t] = s * (1.f / 1024.f);
  }
  __syncthreads();
  float s = 0.f;
  #pragma unroll 8
  for (int k = 0; k < 128; k++) s += xs[k] * W1[k * 256 + t];
  h1[t] = fmaxf(s + b1[t], 0.f);
  __syncthreads();
  if (t < 128) {
    float s2 = 0.f;
    #pragma unroll 8
    for (int k = 0; k < 256; k++) s2 += h1[k] * W2[k * 128 + t];
    h2[t] = fmaxf(s2 + b2[t], 0.f);
  }
  __syncthreads();
  float lg[4];
  #pragma unroll
  for (int q = 0; q < 4; q++) {
    int o = t + (q << 8);
    float s3 = 0.f;
    #pragma unroll 8
    for (int k = 0; k < 128; k++) s3 += h2[k] * Wpi[k * 1024 + o];
    lg[q] = s3 + bpi[o];
  }
  float mx = fmaxf(fmaxf(lg[0], lg[1]), fmaxf(lg[2], lg[3]));
  #pragma unroll
  for (int off = 32; off > 0; off >>= 1) mx = fmaxf(mx, __shfl_down(mx, off, 64));
  if ((t & 63) == 0) red[t >> 6] = mx;
  __syncthreads();
  mx = fmaxf(fmaxf(red[0], red[1]), fmaxf(red[2], red[3]));
  __syncthreads();
  float ex[4]; float sum = 0.f;
  #pragma unroll
  for (int q = 0; q < 4; q++) { ex[q] = __expf(lg[q] - mx); sum += ex[q]; }
  #pragma unroll
  for (int off = 32; off > 0; off >>= 1) sum += __shfl_down(sum, off, 64);
  if ((t & 63) == 0) red[t >> 6] = sum;
  __syncthreads();
  sum = red[0] + red[1] + red[2] + red[3];
  float rs = 1.0f / sum;
  #pragma unroll
  for (int q = 0; q < 4; q++) out[((size_t)b << 10) + t + (q << 8)] = ex[q] * rs;
  __syncthreads();
  float vp = (t < 128) ? h2[t] * Wv[t] : 0.f;
  #pragma unroll
  for (int off = 32; off > 0; off >>= 1) vp += __shfl_down(vp, off, 64);
  if ((t & 63) == 0) red[t >> 6] = vp;
  __syncthreads();
  if (t == 0) out[65536 + b] = red[0] + red[1] + red[2] + red[3] + bv[0];
}

// ======= fused prep: blocks [0,2048) pack adjacency; blocks [2048,3072) featurize =======
// pack and feat are independent -> one dispatch lets the HBM-latency-bound pack stream
// overlap the VALU-bound featurize instead of serializing them.
__global__ __launch_bounds__(256) void k_prep(Params p) {
  __shared__ __align__(16) char smem[512];
  if (blockIdx.x < 2048) {
    // pack: 32 rows/block, wave w handles 8 rows; unroll 4 => 16 dwordx4 in flight/lane
    ushort* pmu = (ushort*)p.pm;
    const int lane = threadIdx.x & 63, w = threadIdx.x >> 6;
    const int r0 = (blockIdx.x << 5) + (w << 3);
    #pragma unroll 4
    for (int rr = 0; rr < 8; ++rr) {
      const int rg = r0 + rr;
      const uint4* arow = (const uint4*)(p.adj + ((size_t)rg << 10));
      uint4 v0 = arow[(lane << 2) | 0], v1 = arow[(lane << 2) | 1];
      uint4 v2 = arow[(lane << 2) | 2], v3 = arow[(lane << 2) | 3];
      unsigned int bits =
          (v0.x) | (v0.y << 1) | (v0.z << 2) | (v0.w << 3) |
          (v1.x << 4) | (v1.y << 5) | (v1.z << 6) | (v1.w << 7) |
          (v2.x << 8) | (v2.y << 9) | (v2.z << 10) | (v2.w << 11) |
          (v3.x << 12) | (v3.y << 13) | (v3.z << 14) | (v3.w << 15);
      pmu[((size_t)rg << 6) + lane] = (ushort)bits;
    }
  } else {
    const int fb = blockIdx.x - 2048;
    #pragma unroll 1
    for (int i = 0; i < 8; ++i)
      feat_group((fb << 3) + i, threadIdx.x, p.nf, p.Win, p.asrc, p.adst,
                 p.x0, p.ai1, p.aj1, p.E1, p.G1, p.F1, p.H1, smem);
  }
}

// ======= remaining plain kernels =======
__global__ __launch_bounds__(256, 3) void k_agg1_w(Params p) {
  __shared__ __align__(16) char smem[24064];
  agg_tile<1>(blockIdx.y, blockIdx.x << 6, smem, p.x0,
              p.ai1, p.E1, p.G1, p.aj1, p.F1, p.H1, p.pm, p.x1, nullptr, 0);
}
__global__ __launch_bounds__(256) void k_scores_w(Params p) {
  __shared__ __align__(16) char smem[512];
  #pragma unroll 1
  for (int i = 0; i < 8; ++i)
    scores_group((blockIdx.x << 3) + i, threadIdx.x, p.x1, p.asrc2, p.adst2,
                 p.ai2, p.aj2, p.E2, p.G2, p.F2, p.H2, smem);
}
__global__ __launch_bounds__(256, 3) void k_agg2_w(Params p) {
  __shared__ __align__(16) char smem[24064];
  agg_tile<2>(blockIdx.y, blockIdx.x << 6, smem, p.x1,
              p.ai2, p.E2, p.G2, p.aj2, p.F2, p.H2, p.pm, nullptr, p.xmp,
              ((int)blockIdx.y << 4) + blockIdx.x);
}
__global__ __launch_bounds__(256) void k_head_w(Params p) {
  __shared__ __align__(16) char smem[2080];
  head_batch(blockIdx.x, threadIdx.x, smem, p.xmp, p.W1, p.b1, p.W2, p.b2,
             p.Wpi, p.bpi, p.Wv, p.bv, p.out);
}

extern "C" void kernel_launch(void* const* d_in, const int* in_sizes, int n_in,
                              void* d_out, int out_size, void* d_ws, size_t ws_size,
                              hipStream_t stream) {
  char* ws = (char*)d_ws;
  Params p;
  p.nf    = (const float*)d_in[0];
  p.adj   = (const int*)  d_in[1];
  p.Win   = (const float*)d_in[2];
  p.asrc  = (const float*)d_in[3];
  p.adst  = (const float*)d_in[4];
  p.asrc2 = (const float*)d_in[5];
  p.adst2 = (const float*)d_in[6];
  p.W1    = (const float*)d_in[7];
  p.b1    = (const float*)d_in[8];
  p.W2    = (const float*)d_in[9];
  p.b2    = (const float*)d_in[10];
  p.Wpi   = (const float*)d_in[11];
  p.bpi   = (const float*)d_in[12];
  p.Wv    = (const float*)d_in[13];
  p.bv    = (const float*)d_in[14];
  p.out   = (float*)d_out;
  p.x0 = (_Float16*)(ws);                                // 16.78 MB
  p.x1 = (_Float16*)(ws + 16777216);                     // 16.78 MB
  p.pm = (u64*)(ws + 33554432);                          // 8.39 MB
  char* S = ws + 41943040;
  p.ai1 = (float*)(S + 0 * 262144);
  p.aj1 = (float*)(S + 1 * 262144);
  p.E1  = (float*)(S + 2 * 262144);
  p.G1  = (float*)(S + 3 * 262144);
  p.F1  = (float*)(S + 4 * 262144);
  p.H1  = (float*)(S + 5 * 262144);
  p.ai2 = (float*)(S + 6 * 262144);
  p.aj2 = (float*)(S + 7 * 262144);
  p.E2  = (float*)(S + 8 * 262144);
  p.G2  = (float*)(S + 9 * 262144);
  p.F2  = (float*)(S + 10 * 262144);
  p.H2  = (float*)(S + 11 * 262144);
  p.xmp = (float*)(S + 12 * 262144);                     // 512 KB partials

  k_prep<<<3072, 256, 0, stream>>>(p);
  k_agg1_w<<<dim3(16, Bn), 256, 0, stream>>>(p);
  k_scores_w<<<1024, 256, 0, stream>>>(p);
  k_agg2_w<<<dim3(16, Bn), 256, 0, stream>>>(p);
  k_head_w<<<Bn, 256, 0, stream>>>(p);
}